// Round 4
// baseline (642.681 us; speedup 1.0000x reference)
//
#include <hip/hip_runtime.h>

// Dims
#define NB 4
#define NTOK 32768
#define BNT 131072      // NB*NTOK
#define CDIM 256
#define HH 8
#define NCOL 768        // 256 fx cols + 512 proj cols

typedef __attribute__((ext_vector_type(8))) __bf16 bf16x8;
typedef __attribute__((ext_vector_type(4))) __bf16 bf16x4;
typedef __attribute__((ext_vector_type(4))) float f32x4;

__device__ inline void gload_lds16(const void* g, void* l) {
    __builtin_amdgcn_global_load_lds(
        (const __attribute__((address_space(1))) void*)g,
        (__attribute__((address_space(3))) void*)l, 16, 0, 0);
}

// ---------------- K0: build combined weight matrix (bf16 hi/lo, transposed) ----------------
// Bt (768 x 512 bf16): row n = output col; cols [0,256)=hi, [256,512)=lo of
//   Bcomb[k][n] where Bcomb cols [0,256)=Wfx^T, [256,768)=Wx^T@Wslice^T per head.
__global__ __launch_bounds__(256) void k0_build(
    const float* __restrict__ Wx, const float* __restrict__ bx,
    const float* __restrict__ Wfx, const float* __restrict__ bfx,
    const float* __restrict__ Wslice, const float* __restrict__ bslice,
    __bf16* __restrict__ Bt, float* __restrict__ bcomb)
{
    int col = blockIdx.x;      // 0..767 (output column n)
    int k = threadIdx.x;       // 0..255 (input channel)
    float acc;
    if (col < 256) {
        acc = Wfx[col * 256 + k];
        if (k == 0) bcomb[col] = bfx[col];
    } else {
        int p = col - 256, h = p >> 6, s = p & 63;
        acc = 0.f;
        #pragma unroll
        for (int d = 0; d < 32; ++d)
            acc += Wx[(h * 32 + d) * 256 + k] * Wslice[s * 32 + d];
        if (k == 0) {
            float bacc = bslice[s];
            #pragma unroll
            for (int d = 0; d < 32; ++d)
                bacc += bx[h * 32 + d] * Wslice[s * 32 + d];
            bcomb[col] = bacc;
        }
    }
    __bf16 hi = (__bf16)acc;
    Bt[(long)col * 512 + k] = hi;
    Bt[(long)col * 512 + 256 + k] = (__bf16)(acc - (float)hi);
}

// ---------------- split-bf16 MFMA GEMM ----------------
// C[m][n] = sum_k A[m][k]*B[k][n] + bias[n].
// B: bf16 [N][2*KO], row n = hi[0,KO) | lo[KO,2KO). 3-term: hh + lh + hl.
// APAIR:  A is bf16 [M][2*KO] (same layout) -> pure global_load_lds staging.
// !APAIR: A is fp32 [M][lda] -> reg-staged fp32->hi/lo split + swizzled ds_write.
// FUSE_SM: wave-uniform epilogue split: n<256 -> fp32 fx to Cf[ldc=256];
//          n>=256 -> temp-softmax over 64-col head block, bf16 hi/lo to Cw[ldc=1024].
// 128x128 tile, 4 waves (2x2), 16x16x32 bf16 MFMA, XOR-swizzled LDS.
template<int NSO, bool APAIR, bool FUSE_SM>
__global__ __launch_bounds__(256) void gemm_split(
    const void* __restrict__ Av, const __bf16* __restrict__ Bt,
    const float* __restrict__ bias, float* __restrict__ Cf,
    __bf16* __restrict__ Cw, const float* __restrict__ temperature,
    int lda, long bStrideB)
{
    constexpr int KO = NSO * 64;
    constexpr int LDB = 2 * KO;
    __shared__ __bf16 sAhi[128 * 64];
    __shared__ __bf16 sAlo[128 * 64];
    __shared__ __bf16 sBhi[128 * 64];
    __shared__ __bf16 sBlo[128 * 64];

    const int tid = threadIdx.x;
    const int lane = tid & 63;
    const int w = tid >> 6;
    const int wr = w >> 1, wc = w & 1;
    const int m0 = blockIdx.y * 128, n0 = blockIdx.x * 128;
    const __bf16* BtB = Bt + ((long)m0 >> 15) * bStrideB;  // per-batch B (K4)

    f32x4 acc[4][4] = {};

    for (int cs = 0; cs < NSO; ++cs) {
        __syncthreads();   // previous compute done; LDS reusable
        // --- stage B (and A if APAIR) via global_load_lds, source pre-swizzled ---
        #pragma unroll
        for (int i = 0; i < 4; ++i) {
            int li = i * 256 + tid;
            int r = li >> 3, c = li & 7;
            int csrc = c ^ (r & 7);
            int lb = (i * 256 + (tid & ~63)) * 16;   // wave-uniform base
            long gb = (long)(n0 + r) * LDB + cs * 64 + csrc * 8;
            gload_lds16(BtB + gb, (char*)sBhi + lb);
            gload_lds16(BtB + KO + gb, (char*)sBlo + lb);
            if constexpr (APAIR) {
                const __bf16* Ab = (const __bf16*)Av;
                long ga = (long)(m0 + r) * LDB + cs * 64 + csrc * 8;
                gload_lds16(Ab + ga, (char*)sAhi + lb);
                gload_lds16(Ab + KO + ga, (char*)sAlo + lb);
            }
        }
        // --- stage A: fp32 -> (hi,lo) bf16, swizzled ds_write (non-pair path) ---
        if constexpr (!APAIR) {
            const float* Af = (const float*)Av;
            #pragma unroll
            for (int i = 0; i < 8; ++i) {
                int li = i * 256 + tid;
                int r = li >> 4, q = li & 15;   // q: 4-float chunk within row
                float4 v = *(const float4*)(Af + (long)(m0 + r) * lda + cs * 64 + q * 4);
                __bf16 h0 = (__bf16)v.x, h1 = (__bf16)v.y,
                       h2 = (__bf16)v.z, h3 = (__bf16)v.w;
                __bf16 l0 = (__bf16)(v.x - (float)h0), l1 = (__bf16)(v.y - (float)h1),
                       l2 = (__bf16)(v.z - (float)h2), l3 = (__bf16)(v.w - (float)h3);
                int byteoff = r * 128 + ((((q >> 1) ^ (r & 7)) << 4)) + (q & 1) * 8;
                *(bf16x4*)((char*)sAhi + byteoff) = (bf16x4){h0, h1, h2, h3};
                *(bf16x4*)((char*)sAlo + byteoff) = (bf16x4){l0, l1, l2, l3};
            }
        }
        __syncthreads();   // drains vmcnt (gload_lds) + lgkmcnt (ds_write)
        // --- compute: 2 k-subs x 16 frag-pairs x 3 MFMAs ---
        #pragma unroll
        for (int ksub = 0; ksub < 2; ++ksub) {
            int cr = ksub * 4 + (lane >> 4);
            bf16x8 ah[4], al[4], bh[4], bl[4];
            #pragma unroll
            for (int mi = 0; mi < 4; ++mi) {
                int r = wr * 64 + mi * 16 + (lane & 15);
                int off = r * 128 + ((cr ^ (r & 7)) << 4);
                ah[mi] = *(const bf16x8*)((const char*)sAhi + off);
                al[mi] = *(const bf16x8*)((const char*)sAlo + off);
            }
            #pragma unroll
            for (int ni = 0; ni < 4; ++ni) {
                int r = wc * 64 + ni * 16 + (lane & 15);
                int off = r * 128 + ((cr ^ (r & 7)) << 4);
                bh[ni] = *(const bf16x8*)((const char*)sBhi + off);
                bl[ni] = *(const bf16x8*)((const char*)sBlo + off);
            }
            #pragma unroll
            for (int mi = 0; mi < 4; ++mi)
                #pragma unroll
                for (int ni = 0; ni < 4; ++ni) {
                    acc[mi][ni] = __builtin_amdgcn_mfma_f32_16x16x32_bf16(ah[mi], bh[ni], acc[mi][ni], 0, 0, 0);
                    acc[mi][ni] = __builtin_amdgcn_mfma_f32_16x16x32_bf16(al[mi], bh[ni], acc[mi][ni], 0, 0, 0);
                    acc[mi][ni] = __builtin_amdgcn_mfma_f32_16x16x32_bf16(ah[mi], bl[ni], acc[mi][ni], 0, 0, 0);
                }
        }
    }
    // --- epilogue: C/D layout col=lane&15, row=(lane>>4)*4+reg ---
    {
        int rbase = m0 + wr * 64 + (lane >> 4) * 4;
        int cbase = n0 + wc * 64 + (lane & 15);
        float bv[4];
        #pragma unroll
        for (int ni = 0; ni < 4; ++ni) bv[ni] = bias[cbase + ni * 16];

        bool proj = FUSE_SM && (n0 + wc * 64) >= 256;   // wave-uniform
        if (proj) {
            int h = (n0 + wc * 64 - 256) >> 6;
            float invt = 1.f / fminf(fmaxf(temperature[h], 0.5f), 5.0f);
            #pragma unroll
            for (int mi = 0; mi < 4; ++mi)
                #pragma unroll
                for (int rr = 0; rr < 4; ++rr) {
                    float v[4];
                    #pragma unroll
                    for (int ni = 0; ni < 4; ++ni)
                        v[ni] = (acc[mi][ni][rr] + bv[ni]) * invt;
                    float m = fmaxf(fmaxf(v[0], v[1]), fmaxf(v[2], v[3]));
                    #pragma unroll
                    for (int o = 1; o < 16; o <<= 1) m = fmaxf(m, __shfl_xor(m, o));
                    float e[4], s = 0.f;
                    #pragma unroll
                    for (int ni = 0; ni < 4; ++ni) { e[ni] = __expf(v[ni] - m); s += e[ni]; }
                    #pragma unroll
                    for (int o = 1; o < 16; o <<= 1) s += __shfl_xor(s, o);
                    float rs = 1.f / s;
                    long row = rbase + mi * 16 + rr;
                    #pragma unroll
                    for (int ni = 0; ni < 4; ++ni) {
                        float val = e[ni] * rs;
                        __bf16 hi = (__bf16)val;
                        __bf16 lo = (__bf16)(val - (float)hi);
                        long cw = cbase + ni * 16 - 256;
                        Cw[row * 1024 + cw] = hi;
                        Cw[row * 1024 + 512 + cw] = lo;
                    }
                }
        } else {
            #pragma unroll
            for (int mi = 0; mi < 4; ++mi)
                #pragma unroll
                for (int ni = 0; ni < 4; ++ni)
                    #pragma unroll
                    for (int rr = 0; rr < 4; ++rr)
                        Cf[(long)(rbase + mi * 16 + rr) * 256 + cbase + ni * 16] =
                            acc[mi][ni][rr] + bv[ni];
        }
    }
}

// ---------------- K1c: accumulate slice_token partials + slice_norm partials ----------------
__global__ __launch_bounds__(256) void k1c_accum(
    const float* __restrict__ yfx, const __bf16* __restrict__ yw,
    float* __restrict__ partials)
{
    int chunk = blockIdx.x & 63;
    int bh = blockIdx.x >> 6;
    int b = bh >> 3, h = bh & 7;
    long tbase = (long)b * NTOK + (long)chunk * 512;

    __shared__ float wl[8][64];
    __shared__ float fxl[8][32];

    int tid = threadIdx.x;
    int d = tid & 31;
    int sg = tid >> 5;  // 0..7

    float acc[8] = {0, 0, 0, 0, 0, 0, 0, 0};
    float nacc = 0.f;

    for (int g = 0; g < 64; ++g) {
        long t0 = tbase + g * 8;
        {
            int idx = tid;
            #pragma unroll
            for (int r = 0; r < 2; ++r, idx += 256) {
                int ti = idx >> 6, s = idx & 63;
                long base = (t0 + ti) * 1024 + h * 64 + s;
                wl[ti][s] = (float)yw[base] + (float)yw[base + 512];
            }
            int ti = tid >> 5, dd = tid & 31;
            fxl[ti][dd] = yfx[(t0 + ti) * 256 + h * 32 + dd];
        }
        __syncthreads();
        #pragma unroll
        for (int ti = 0; ti < 8; ++ti) {
            float f = fxl[ti][d];
            #pragma unroll
            for (int k = 0; k < 8; ++k)
                acc[k] += wl[ti][sg + 8 * k] * f;
        }
        if (tid < 64) {
            #pragma unroll
            for (int ti = 0; ti < 8; ++ti) nacc += wl[ti][tid];
        }
        __syncthreads();
    }

    float* P = partials + ((long)bh * 64 + chunk) * 2112;
    #pragma unroll
    for (int k = 0; k < 8; ++k) {
        int s = sg + 8 * k;
        P[s * 32 + d] = acc[k];
    }
    if (tid < 64) P[2048 + tid] = nacc;
}

// ---------------- K3: reduce partials, slice attention, build OT2T (bf16 hi/lo) ----------------
// OT2T[b][c][k'] : k'=h*64+s -> hi, k'=512+h*64+s -> lo of
//   sum_d out_tok[b,h,s,d] * Wout[c][h*32+d]
__global__ __launch_bounds__(256) void k3_slice(
    const float* __restrict__ partials,
    const float* __restrict__ Wqkv,
    const float* __restrict__ Wout,
    __bf16* __restrict__ OT2T)
{
    __shared__ float smem[14720];
    float* st = smem;          // 64*33
    float* q  = smem + 2112;
    float* kk = smem + 4224;
    float* v  = smem + 6336;
    float* L  = smem + 8448;   // 64*65
    float* red = L;
    float* ot = smem + 12608;  // 64*33

    int bh = blockIdx.x;
    int b = bh >> 3, h = bh & 7;
    int tid = threadIdx.x;

    for (int idx = tid; idx < 2112; idx += 256) {
        float s = 0.f;
        const float* P = partials + (long)bh * 64 * 2112 + idx;
        for (int c = 0; c < 64; ++c) s += P[c * 2112];
        red[idx] = s;
    }
    __syncthreads();
    for (int idx = tid; idx < 2048; idx += 256) {
        int s = idx >> 5, d = idx & 31;
        st[s * 33 + d] = red[idx] / (red[2048 + s] + 0.01f);
    }
    __syncthreads();
    for (int idx = tid; idx < 64 * 96; idx += 256) {
        int s = idx / 96, e = idx % 96;
        float acc = 0.f;
        #pragma unroll
        for (int d = 0; d < 32; ++d) acc += st[s * 33 + d] * Wqkv[e * 32 + d];
        if (e < 32)       q[s * 33 + e] = acc;
        else if (e < 64)  kk[s * 33 + (e - 32)] = acc;
        else              v[s * 33 + (e - 64)] = acc;
    }
    __syncthreads();
    for (int idx = tid; idx < 4096; idx += 256) {
        int i = idx >> 6, j = idx & 63;
        float acc = 0.f;
        #pragma unroll
        for (int d = 0; d < 32; ++d) acc += q[i * 33 + d] * kk[j * 33 + d];
        L[i * 65 + j] = acc * 0.17677669529663687f;
    }
    __syncthreads();
    {
        int lane = tid & 63, wid = tid >> 6;
        for (int r = wid; r < 64; r += 4) {
            float x = L[r * 65 + lane];
            float m = x;
            #pragma unroll
            for (int o = 32; o; o >>= 1) m = fmaxf(m, __shfl_xor(m, o));
            float e = __expf(x - m);
            float ss2 = e;
            #pragma unroll
            for (int o = 32; o; o >>= 1) ss2 += __shfl_xor(ss2, o);
            L[r * 65 + lane] = e / ss2;
        }
    }
    __syncthreads();
    for (int idx = tid; idx < 2048; idx += 256) {
        int s = idx >> 5, d = idx & 31;
        float acc = 0.f;
        #pragma unroll
        for (int j = 0; j < 64; ++j) acc += L[s * 65 + j] * v[j * 33 + d];
        ot[s * 33 + d] = acc;
    }
    __syncthreads();
    float* Wo = smem;  // 256*33
    for (int idx = tid; idx < 8192; idx += 256) {
        int c = idx >> 5, d = idx & 31;
        Wo[c * 33 + d] = Wout[c * 256 + h * 32 + d];
    }
    __syncthreads();
    {
        int c = tid;
        __bf16* O = OT2T + (long)b * 262144 + (long)c * 1024 + h * 64;
        for (int s = 0; s < 64; ++s) {
            float acc = 0.f;
            #pragma unroll
            for (int d = 0; d < 32; ++d) acc += ot[s * 33 + d] * Wo[c * 33 + d];
            __bf16 hi = (__bf16)acc;
            O[s] = hi;
            O[512 + s] = (__bf16)(acc - (float)hi);
        }
    }
}

extern "C" void kernel_launch(void* const* d_in, const int* in_sizes, int n_in,
                              void* d_out, int out_size, void* d_ws, size_t ws_size,
                              hipStream_t stream) {
    const float* x           = (const float*)d_in[0];
    const float* Wx          = (const float*)d_in[1];
    const float* bx          = (const float*)d_in[2];
    const float* Wfx         = (const float*)d_in[3];
    const float* bfx         = (const float*)d_in[4];
    const float* Wslice      = (const float*)d_in[5];
    const float* bslice      = (const float*)d_in[6];
    const float* Wqkv        = (const float*)d_in[7];
    const float* Wout        = (const float*)d_in[8];
    const float* bout        = (const float*)d_in[9];
    const float* temperature = (const float*)d_in[10];
    float* out = (float*)d_out;

    char* ws = (char*)d_ws;
    float*  yfx      = (float*)(ws);                                   // 131072*256 f32   = 134217728 B
    __bf16* yw       = (__bf16*)(ws + 134217728ULL);                   // 131072*1024 bf16 = 268435456 B
    float*  partials = (float*)(ws + 402653184ULL);                    // 32*64*2112 f32   = 17301504 B
    __bf16* BtK1a    = (__bf16*)(ws + 419954688ULL);                   // 768*512 bf16     = 786432 B
    float*  bcomb    = (float*)(ws + 420741120ULL);                    // 768 f32          = 3072 B
    __bf16* OT2T     = (__bf16*)(ws + 420744192ULL);                   // 4*256*1024 bf16  = 2097152 B (end 422841344)

    // K0: combined weights (bf16 hi/lo, [n][k] layout)
    k0_build<<<768, 256, 0, stream>>>(Wx, bx, Wfx, bfx, Wslice, bslice, BtK1a, bcomb);

    // K1a: [fx | w] = x @ Bcomb + bcomb, softmax fused on proj cols
    //      fx -> yfx (fp32), w -> yw (bf16 hi/lo pairs, gload-ready)
    gemm_split<4, false, true><<<dim3(NCOL / 128, BNT / 128), 256, 0, stream>>>(
        x, BtK1a, bcomb, yfx, yw, temperature, CDIM, 0L);

    // K1c: pooled partial sums (w reconstructed from hi+lo)
    k1c_accum<<<32 * 64, 256, 0, stream>>>(yfx, yw, partials);

    // K3: slice attention + OT2T (bf16 hi/lo transposed)
    k3_slice<<<32, 256, 0, stream>>>(partials, Wqkv, Wout, OT2T);

    // K4: out = w @ OT2 + bout  (M=131072, N=256, K=512), pure gload_lds staging
    gemm_split<8, true, false><<<dim3(256 / 128, BNT / 128), 256, 0, stream>>>(
        yw, OT2T, bout, out, nullptr, nullptr, 0, 262144L);
}

// Round 5
// 531.601 us; speedup vs baseline: 1.2090x; 1.2090x over previous
//
#include <hip/hip_runtime.h>

// Dims
#define NB 4
#define NTOK 32768
#define BNT 131072      // NB*NTOK
#define CDIM 256
#define HH 8
#define NCOL 768        // 256 fx cols + 512 proj cols

typedef _Float16 f16;
typedef __attribute__((ext_vector_type(8))) _Float16 f16x8;
typedef __attribute__((ext_vector_type(4))) _Float16 f16x4;
typedef __attribute__((ext_vector_type(4))) float f32x4;

__device__ inline void gload_lds16(const void* g, void* l) {
    __builtin_amdgcn_global_load_lds(
        (const __attribute__((address_space(1))) void*)g,
        (__attribute__((address_space(3))) void*)l, 16, 0, 0);
}

// ---------------- K0: build combined weight matrix (f16 hi/lo, transposed) ----------------
// Bt (768 x 512 f16): row n: [0,256)=hi, [256,512)=lo of Bcomb[k][n], where
// Bcomb cols [0,256)=Wfx^T, [256,768)=Wx^T@Wslice^T per head.
__global__ __launch_bounds__(256) void k0_build(
    const float* __restrict__ Wx, const float* __restrict__ bx,
    const float* __restrict__ Wfx, const float* __restrict__ bfx,
    const float* __restrict__ Wslice, const float* __restrict__ bslice,
    f16* __restrict__ Bt, float* __restrict__ bcomb)
{
    int col = blockIdx.x;      // 0..767 (output column n)
    int k = threadIdx.x;       // 0..255 (input channel)
    float acc;
    if (col < 256) {
        acc = Wfx[col * 256 + k];
        if (k == 0) bcomb[col] = bfx[col];
    } else {
        int p = col - 256, h = p >> 6, s = p & 63;
        acc = 0.f;
        #pragma unroll
        for (int d = 0; d < 32; ++d)
            acc += Wx[(h * 32 + d) * 256 + k] * Wslice[s * 32 + d];
        if (k == 0) {
            float bacc = bslice[s];
            #pragma unroll
            for (int d = 0; d < 32; ++d)
                bacc += bx[h * 32 + d] * Wslice[s * 32 + d];
            bcomb[col] = bacc;
        }
    }
    f16 hi = (f16)acc;
    Bt[(long)col * 512 + k] = hi;
    Bt[(long)col * 512 + 256 + k] = (f16)(acc - (float)hi);
}

// ---------------- f16 2-term MFMA GEMM ----------------
// C[m][n] = sum_k A[m][k]*B[k][n] + bias[n].
// B: f16 [N][2*KO], row n = hi[0,KO) | lo[KO,2KO). 2-term: a*bh + a*bl (B exact
// to 2^-24; error = dropped a_lo*b ~ 2^-13 relative).
// APAIR:  A is f16 [M][KO] -> pure global_load_lds staging.
// !APAIR: A is fp32 [M][CDIM] -> reg-staged fp32->f16 + swizzled ds_write.
// FUSE_SM: n<256 -> f16 fx to Cfx[ld 256]; n>=256 -> temp-softmax over 64-col
//          head block, f16 to Cw[ld 512]. Else fp32 to Cf[ld 256].
// 128x128 tile, 4 waves (2x2), 16x16x32 f16 MFMA, XOR-swizzled LDS,
// XCD-bijective block swizzle (nwg%8==0 for all launches here).
template<int NSO, bool APAIR, bool FUSE_SM>
__global__ __launch_bounds__(256) void gemm_split(
    const void* __restrict__ Av, const f16* __restrict__ Bt,
    const float* __restrict__ bias, float* __restrict__ Cf,
    f16* __restrict__ Cfx, f16* __restrict__ Cw,
    const float* __restrict__ temperature, long bStrideB)
{
    constexpr int KO = NSO * 64;
    constexpr int LDB = 2 * KO;
    __shared__ f16 sA[128 * 64];
    __shared__ f16 sBhi[128 * 64];
    __shared__ f16 sBlo[128 * 64];

    const int tid = threadIdx.x;
    const int lane = tid & 63;
    const int w = tid >> 6;
    const int wr = w >> 1, wc = w & 1;

    // XCD-aware bijective swizzle: each XCD gets a contiguous chunk of tiles.
    const int nx = gridDim.x;
    const int nwg = nx * gridDim.y;
    const int lid = blockIdx.y * nx + blockIdx.x;
    const int swz = (lid & 7) * (nwg >> 3) + (lid >> 3);
    const int m0 = (swz / nx) * 128, n0 = (swz % nx) * 128;

    const f16* BtB = Bt + ((long)m0 >> 15) * bStrideB;  // per-batch B (K4)

    f32x4 acc[4][4] = {};

    for (int cs = 0; cs < NSO; ++cs) {
        __syncthreads();   // previous compute done; LDS reusable
        // --- stage B hi/lo (and A if APAIR) via global_load_lds, pre-swizzled src ---
        #pragma unroll
        for (int i = 0; i < 4; ++i) {
            int li = i * 256 + tid;
            int r = li >> 3, c = li & 7;
            int csrc = c ^ (r & 7);
            int lb = (i * 256 + (tid & ~63)) * 16;   // wave-uniform base
            long gb = (long)(n0 + r) * LDB + cs * 64 + csrc * 8;
            gload_lds16(BtB + gb, (char*)sBhi + lb);
            gload_lds16(BtB + KO + gb, (char*)sBlo + lb);
            if constexpr (APAIR) {
                const f16* Ab = (const f16*)Av;
                long ga = (long)(m0 + r) * KO + cs * 64 + csrc * 8;
                gload_lds16(Ab + ga, (char*)sA + lb);
            }
        }
        // --- stage A: fp32 -> f16, swizzled ds_write (non-pair path) ---
        if constexpr (!APAIR) {
            const float* Af = (const float*)Av;
            #pragma unroll
            for (int i = 0; i < 8; ++i) {
                int li = i * 256 + tid;
                int r = li >> 4, q = li & 15;   // q: 4-float chunk within row
                float4 v = *(const float4*)(Af + (long)(m0 + r) * CDIM + cs * 64 + q * 4);
                f16 h0 = (f16)v.x, h1 = (f16)v.y, h2 = (f16)v.z, h3 = (f16)v.w;
                int byteoff = r * 128 + ((((q >> 1) ^ (r & 7)) << 4)) + (q & 1) * 8;
                *(f16x4*)((char*)sA + byteoff) = (f16x4){h0, h1, h2, h3};
            }
        }
        __syncthreads();   // drains vmcnt (gload_lds) + lgkmcnt (ds_write)
        // --- compute: 2 k-subs x 16 frag-pairs x 2 MFMAs ---
        #pragma unroll
        for (int ksub = 0; ksub < 2; ++ksub) {
            int cr = ksub * 4 + (lane >> 4);
            f16x8 a[4], bh[4], bl[4];
            #pragma unroll
            for (int mi = 0; mi < 4; ++mi) {
                int r = wr * 64 + mi * 16 + (lane & 15);
                int off = r * 128 + ((cr ^ (r & 7)) << 4);
                a[mi] = *(const f16x8*)((const char*)sA + off);
            }
            #pragma unroll
            for (int ni = 0; ni < 4; ++ni) {
                int r = wc * 64 + ni * 16 + (lane & 15);
                int off = r * 128 + ((cr ^ (r & 7)) << 4);
                bh[ni] = *(const f16x8*)((const char*)sBhi + off);
                bl[ni] = *(const f16x8*)((const char*)sBlo + off);
            }
            #pragma unroll
            for (int mi = 0; mi < 4; ++mi)
                #pragma unroll
                for (int ni = 0; ni < 4; ++ni) {
                    acc[mi][ni] = __builtin_amdgcn_mfma_f32_16x16x32_f16(a[mi], bh[ni], acc[mi][ni], 0, 0, 0);
                    acc[mi][ni] = __builtin_amdgcn_mfma_f32_16x16x32_f16(a[mi], bl[ni], acc[mi][ni], 0, 0, 0);
                }
        }
    }
    // --- epilogue: C/D layout col=lane&15, row=(lane>>4)*4+reg ---
    {
        int rbase = m0 + wr * 64 + (lane >> 4) * 4;
        int cbase = n0 + wc * 64 + (lane & 15);
        float bv[4];
        #pragma unroll
        for (int ni = 0; ni < 4; ++ni) bv[ni] = bias[cbase + ni * 16];

        if constexpr (FUSE_SM) {
            bool proj = (n0 + wc * 64) >= 256;   // wave-uniform
            if (proj) {
                int h = (n0 + wc * 64 - 256) >> 6;
                float invt = 1.f / fminf(fmaxf(temperature[h], 0.5f), 5.0f);
                #pragma unroll
                for (int mi = 0; mi < 4; ++mi)
                    #pragma unroll
                    for (int rr = 0; rr < 4; ++rr) {
                        float v[4];
                        #pragma unroll
                        for (int ni = 0; ni < 4; ++ni)
                            v[ni] = (acc[mi][ni][rr] + bv[ni]) * invt;
                        float m = fmaxf(fmaxf(v[0], v[1]), fmaxf(v[2], v[3]));
                        #pragma unroll
                        for (int o = 1; o < 16; o <<= 1) m = fmaxf(m, __shfl_xor(m, o));
                        float e[4], s = 0.f;
                        #pragma unroll
                        for (int ni = 0; ni < 4; ++ni) { e[ni] = __expf(v[ni] - m); s += e[ni]; }
                        #pragma unroll
                        for (int o = 1; o < 16; o <<= 1) s += __shfl_xor(s, o);
                        float rs = 1.f / s;
                        long row = rbase + mi * 16 + rr;
                        #pragma unroll
                        for (int ni = 0; ni < 4; ++ni)
                            Cw[row * 512 + cbase + ni * 16 - 256] = (f16)(e[ni] * rs);
                    }
            } else {
                #pragma unroll
                for (int mi = 0; mi < 4; ++mi)
                    #pragma unroll
                    for (int ni = 0; ni < 4; ++ni)
                        #pragma unroll
                        for (int rr = 0; rr < 4; ++rr)
                            Cfx[(long)(rbase + mi * 16 + rr) * 256 + cbase + ni * 16] =
                                (f16)(acc[mi][ni][rr] + bv[ni]);
            }
        } else {
            #pragma unroll
            for (int mi = 0; mi < 4; ++mi)
                #pragma unroll
                for (int ni = 0; ni < 4; ++ni)
                    #pragma unroll
                    for (int rr = 0; rr < 4; ++rr)
                        Cf[(long)(rbase + mi * 16 + rr) * 256 + cbase + ni * 16] =
                            acc[mi][ni][rr] + bv[ni];
        }
    }
}

// ---------------- K1c: accumulate slice_token partials + slice_norm partials ----------------
__global__ __launch_bounds__(256) void k1c_accum(
    const f16* __restrict__ yfx, const f16* __restrict__ yw,
    float* __restrict__ partials)
{
    int chunk = blockIdx.x & 63;
    int bh = blockIdx.x >> 6;
    int b = bh >> 3, h = bh & 7;
    long tbase = (long)b * NTOK + (long)chunk * 512;

    __shared__ float wl[8][64];
    __shared__ float fxl[8][32];

    int tid = threadIdx.x;
    int d = tid & 31;
    int sg = tid >> 5;  // 0..7

    float acc[8] = {0, 0, 0, 0, 0, 0, 0, 0};
    float nacc = 0.f;

    for (int g = 0; g < 64; ++g) {
        long t0 = tbase + g * 8;
        {
            int idx = tid;
            #pragma unroll
            for (int r = 0; r < 2; ++r, idx += 256) {
                int ti = idx >> 6, s = idx & 63;
                wl[ti][s] = (float)yw[(t0 + ti) * 512 + h * 64 + s];
            }
            int ti = tid >> 5, dd = tid & 31;
            fxl[ti][dd] = (float)yfx[(t0 + ti) * 256 + h * 32 + dd];
        }
        __syncthreads();
        #pragma unroll
        for (int ti = 0; ti < 8; ++ti) {
            float f = fxl[ti][d];
            #pragma unroll
            for (int k = 0; k < 8; ++k)
                acc[k] += wl[ti][sg + 8 * k] * f;
        }
        if (tid < 64) {
            #pragma unroll
            for (int ti = 0; ti < 8; ++ti) nacc += wl[ti][tid];
        }
        __syncthreads();
    }

    float* P = partials + ((long)bh * 64 + chunk) * 2112;
    #pragma unroll
    for (int k = 0; k < 8; ++k) {
        int s = sg + 8 * k;
        P[s * 32 + d] = acc[k];
    }
    if (tid < 64) P[2048 + tid] = nacc;
}

// ---------------- K3: reduce partials, slice attention, build OT2T (f16 hi/lo) ----------------
// OT2T[b][c][k'] : k'=h*64+s -> hi, k'=512+h*64+s -> lo of
//   sum_d out_tok[b,h,s,d] * Wout[c][h*32+d]
__global__ __launch_bounds__(256) void k3_slice(
    const float* __restrict__ partials,
    const float* __restrict__ Wqkv,
    const float* __restrict__ Wout,
    f16* __restrict__ OT2T)
{
    __shared__ float smem[14720];
    float* st = smem;          // 64*33
    float* q  = smem + 2112;
    float* kk = smem + 4224;
    float* v  = smem + 6336;
    float* L  = smem + 8448;   // 64*65
    float* red = L;
    float* ot = smem + 12608;  // 64*33

    int bh = blockIdx.x;
    int b = bh >> 3, h = bh & 7;
    int tid = threadIdx.x;

    for (int idx = tid; idx < 2112; idx += 256) {
        float s = 0.f;
        const float* P = partials + (long)bh * 64 * 2112 + idx;
        for (int c = 0; c < 64; ++c) s += P[c * 2112];
        red[idx] = s;
    }
    __syncthreads();
    for (int idx = tid; idx < 2048; idx += 256) {
        int s = idx >> 5, d = idx & 31;
        st[s * 33 + d] = red[idx] / (red[2048 + s] + 0.01f);
    }
    __syncthreads();
    for (int idx = tid; idx < 64 * 96; idx += 256) {
        int s = idx / 96, e = idx % 96;
        float acc = 0.f;
        #pragma unroll
        for (int d = 0; d < 32; ++d) acc += st[s * 33 + d] * Wqkv[e * 32 + d];
        if (e < 32)       q[s * 33 + e] = acc;
        else if (e < 64)  kk[s * 33 + (e - 32)] = acc;
        else              v[s * 33 + (e - 64)] = acc;
    }
    __syncthreads();
    for (int idx = tid; idx < 4096; idx += 256) {
        int i = idx >> 6, j = idx & 63;
        float acc = 0.f;
        #pragma unroll
        for (int d = 0; d < 32; ++d) acc += q[i * 33 + d] * kk[j * 33 + d];
        L[i * 65 + j] = acc * 0.17677669529663687f;
    }
    __syncthreads();
    {
        int lane = tid & 63, wid = tid >> 6;
        for (int r = wid; r < 64; r += 4) {
            float x = L[r * 65 + lane];
            float m = x;
            #pragma unroll
            for (int o = 32; o; o >>= 1) m = fmaxf(m, __shfl_xor(m, o));
            float e = __expf(x - m);
            float ss2 = e;
            #pragma unroll
            for (int o = 32; o; o >>= 1) ss2 += __shfl_xor(ss2, o);
            L[r * 65 + lane] = e / ss2;
        }
    }
    __syncthreads();
    for (int idx = tid; idx < 2048; idx += 256) {
        int s = idx >> 5, d = idx & 31;
        float acc = 0.f;
        #pragma unroll
        for (int j = 0; j < 64; ++j) acc += L[s * 65 + j] * v[j * 33 + d];
        ot[s * 33 + d] = acc;
    }
    __syncthreads();
    float* Wo = smem;  // 256*33
    for (int idx = tid; idx < 8192; idx += 256) {
        int c = idx >> 5, d = idx & 31;
        Wo[c * 33 + d] = Wout[c * 256 + h * 32 + d];
    }
    __syncthreads();
    {
        int c = tid;
        f16* O = OT2T + (long)b * 262144 + (long)c * 1024 + h * 64;
        for (int s = 0; s < 64; ++s) {
            float acc = 0.f;
            #pragma unroll
            for (int d = 0; d < 32; ++d) acc += ot[s * 33 + d] * Wo[c * 33 + d];
            f16 hi = (f16)acc;
            O[s] = hi;
            O[512 + s] = (f16)(acc - (float)hi);
        }
    }
}

extern "C" void kernel_launch(void* const* d_in, const int* in_sizes, int n_in,
                              void* d_out, int out_size, void* d_ws, size_t ws_size,
                              hipStream_t stream) {
    const float* x           = (const float*)d_in[0];
    const float* Wx          = (const float*)d_in[1];
    const float* bx          = (const float*)d_in[2];
    const float* Wfx         = (const float*)d_in[3];
    const float* bfx         = (const float*)d_in[4];
    const float* Wslice      = (const float*)d_in[5];
    const float* bslice      = (const float*)d_in[6];
    const float* Wqkv        = (const float*)d_in[7];
    const float* Wout        = (const float*)d_in[8];
    const float* bout        = (const float*)d_in[9];
    const float* temperature = (const float*)d_in[10];
    float* out = (float*)d_out;

    char* ws = (char*)d_ws;
    f16*   yfx      = (f16*)(ws);                     // 131072*256 f16  =  67108864 B
    f16*   yw       = (f16*)(ws + 67108864ULL);       // 131072*512 f16  = 134217728 B
    float* partials = (float*)(ws + 201326592ULL);    // 32*64*2112 f32  =  17301504 B
    f16*   Bt       = (f16*)(ws + 218628096ULL);      // 768*512 f16     =    786432 B
    float* bcomb    = (float*)(ws + 219414528ULL);    // 768 f32         =      3072 B
    f16*   OT2T     = (f16*)(ws + 219417600ULL);      // 4*256*1024 f16  =   2097152 B (end 221514752)

    // K0: combined weights (f16 hi/lo, [n][k] layout)
    k0_build<<<768, 256, 0, stream>>>(Wx, bx, Wfx, bfx, Wslice, bslice, Bt, bcomb);

    // K1a: [fx | w] = x @ Bcomb + bcomb, softmax fused on proj cols
    //      fx -> yfx (f16), w -> yw (f16, gload-ready)
    gemm_split<4, false, true><<<dim3(NCOL / 128, BNT / 128), 256, 0, stream>>>(
        x, Bt, bcomb, nullptr, yfx, yw, temperature, 0L);

    // K1c: pooled partial sums
    k1c_accum<<<32 * 64, 256, 0, stream>>>(yfx, yw, partials);

    // K3: slice attention + OT2T (f16 hi/lo transposed)
    k3_slice<<<32, 256, 0, stream>>>(partials, Wqkv, Wout, OT2T);

    // K4: out = w @ OT2 + bout  (M=131072, N=256, K=512), pure gload_lds staging
    gemm_split<8, true, false><<<dim3(256 / 128, BNT / 128), 256, 0, stream>>>(
        yw, OT2T, bout, out, nullptr, nullptr, nullptr, 262144L);
}

// Round 6
// 512.883 us; speedup vs baseline: 1.2531x; 1.0365x over previous
//
#include <hip/hip_runtime.h>

// Dims
#define NB 4
#define NTOK 32768
#define BNT 131072      // NB*NTOK
#define CDIM 256
#define HH 8
#define NCOL 768        // 256 fx cols + 512 proj cols

typedef _Float16 f16;
typedef __attribute__((ext_vector_type(8))) _Float16 f16x8;
typedef __attribute__((ext_vector_type(4))) _Float16 f16x4;
typedef __attribute__((ext_vector_type(4))) float f32x4;

__device__ inline void gload_lds16(const void* g, void* l) {
    __builtin_amdgcn_global_load_lds(
        (const __attribute__((address_space(1))) void*)g,
        (__attribute__((address_space(3))) void*)l, 16, 0, 0);
}

// ---------------- xcvt: x fp32 -> f16 (row-major, gload-ready) ----------------
__global__ __launch_bounds__(256) void xcvt(
    const float* __restrict__ x, f16* __restrict__ xf)
{
    long i = (long)blockIdx.x * 256 + threadIdx.x;
    const long stride = (long)gridDim.x * 256;
    const long n4 = (long)BNT * CDIM / 4;
    for (; i < n4; i += stride) {
        float4 v = ((const float4*)x)[i];
        f16x4 o = {(f16)v.x, (f16)v.y, (f16)v.z, (f16)v.w};
        *(f16x4*)(xf + i * 4) = o;
    }
}

// ---------------- K0: build combined weight matrix (f16, transposed) ----------------
// Bt (768 x 256 f16): row n = output col n of Bcomb[k][n], where Bcomb cols
// [0,256)=Wfx^T, [256,768)=Wx^T@Wslice^T per head.
__global__ __launch_bounds__(256) void k0_build(
    const float* __restrict__ Wx, const float* __restrict__ bx,
    const float* __restrict__ Wfx, const float* __restrict__ bfx,
    const float* __restrict__ Wslice, const float* __restrict__ bslice,
    f16* __restrict__ Bt, float* __restrict__ bcomb)
{
    int col = blockIdx.x;      // 0..767 (output column n)
    int k = threadIdx.x;       // 0..255 (input channel)
    float acc;
    if (col < 256) {
        acc = Wfx[col * 256 + k];
        if (k == 0) bcomb[col] = bfx[col];
    } else {
        int p = col - 256, h = p >> 6, s = p & 63;
        acc = 0.f;
        #pragma unroll
        for (int d = 0; d < 32; ++d)
            acc += Wx[(h * 32 + d) * 256 + k] * Wslice[s * 32 + d];
        if (k == 0) {
            float bacc = bslice[s];
            #pragma unroll
            for (int d = 0; d < 32; ++d)
                bacc += bx[h * 32 + d] * Wslice[s * 32 + d];
            bcomb[col] = bacc;
        }
    }
    Bt[(long)col * 256 + k] = (f16)acc;
}

// ---------------- f16 MFMA GEMM, pure global_load_lds staging ----------------
// C[m][n] = sum_k A[m][k]*B[k][n] + bias[n]; A f16 [M][KO], Bt f16 [N][KO].
// FUSE_SM: n<256 -> f16 fx to Cfx[ld 256]; n>=256 -> temp-softmax over 64-col
//          head block, f16 to Cw[ld 512]. Else fp32 to Cf[ld 256].
// 128x128 tile, 4 waves (2x2), 16x16x32 f16 MFMA, XOR-swizzled LDS (via
// pre-swizzled global source), XCD-bijective block swizzle (nwg%8==0).
template<int NSO, bool FUSE_SM>
__global__ __launch_bounds__(256) void gemm_f16(
    const f16* __restrict__ A, const f16* __restrict__ Bt,
    const float* __restrict__ bias, float* __restrict__ Cf,
    f16* __restrict__ Cfx, f16* __restrict__ Cw,
    const float* __restrict__ temperature, long bStrideB)
{
    constexpr int KO = NSO * 64;
    __shared__ f16 sA[128 * 64];
    __shared__ f16 sB[128 * 64];

    const int tid = threadIdx.x;
    const int lane = tid & 63;
    const int w = tid >> 6;
    const int wr = w >> 1, wc = w & 1;

    // XCD-aware bijective swizzle: each XCD gets a contiguous chunk of tiles.
    const int nx = gridDim.x;
    const int nwg = nx * gridDim.y;
    const int lid = blockIdx.y * nx + blockIdx.x;
    const int swz = (lid & 7) * (nwg >> 3) + (lid >> 3);
    const int m0 = (swz / nx) * 128, n0 = (swz % nx) * 128;

    const f16* BtB = Bt + ((long)m0 >> 15) * bStrideB;  // per-batch B (K4)

    f32x4 acc[4][4] = {};

    for (int cs = 0; cs < NSO; ++cs) {
        __syncthreads();   // previous compute done; LDS reusable
        // --- stage A and B via global_load_lds, source pre-swizzled ---
        #pragma unroll
        for (int i = 0; i < 4; ++i) {
            int li = i * 256 + tid;
            int r = li >> 3, c = li & 7;
            int csrc = c ^ (r & 7);
            int lb = (i * 256 + (tid & ~63)) * 16;   // wave-uniform base
            long off = cs * 64 + csrc * 8;
            gload_lds16(A + (long)(m0 + r) * KO + off, (char*)sA + lb);
            gload_lds16(BtB + (long)(n0 + r) * KO + off, (char*)sB + lb);
        }
        __syncthreads();   // drains vmcnt (gload_lds)
        // --- compute: 2 k-subs x 16 MFMAs ---
        #pragma unroll
        for (int ksub = 0; ksub < 2; ++ksub) {
            int cr = ksub * 4 + (lane >> 4);
            f16x8 a[4], b[4];
            #pragma unroll
            for (int mi = 0; mi < 4; ++mi) {
                int r = wr * 64 + mi * 16 + (lane & 15);
                int off = r * 128 + ((cr ^ (r & 7)) << 4);
                a[mi] = *(const f16x8*)((const char*)sA + off);
            }
            #pragma unroll
            for (int ni = 0; ni < 4; ++ni) {
                int r = wc * 64 + ni * 16 + (lane & 15);
                int off = r * 128 + ((cr ^ (r & 7)) << 4);
                b[ni] = *(const f16x8*)((const char*)sB + off);
            }
            #pragma unroll
            for (int mi = 0; mi < 4; ++mi)
                #pragma unroll
                for (int ni = 0; ni < 4; ++ni)
                    acc[mi][ni] = __builtin_amdgcn_mfma_f32_16x16x32_f16(a[mi], b[ni], acc[mi][ni], 0, 0, 0);
        }
    }
    // --- epilogue: C/D layout col=lane&15, row=(lane>>4)*4+reg ---
    {
        int rbase = m0 + wr * 64 + (lane >> 4) * 4;
        int cbase = n0 + wc * 64 + (lane & 15);
        float bv[4];
        #pragma unroll
        for (int ni = 0; ni < 4; ++ni) bv[ni] = bias[cbase + ni * 16];

        if constexpr (FUSE_SM) {
            bool proj = (n0 + wc * 64) >= 256;   // wave-uniform
            if (proj) {
                int h = (n0 + wc * 64 - 256) >> 6;
                float invt = 1.f / fminf(fmaxf(temperature[h], 0.5f), 5.0f);
                #pragma unroll
                for (int mi = 0; mi < 4; ++mi)
                    #pragma unroll
                    for (int rr = 0; rr < 4; ++rr) {
                        float v[4];
                        #pragma unroll
                        for (int ni = 0; ni < 4; ++ni)
                            v[ni] = (acc[mi][ni][rr] + bv[ni]) * invt;
                        float m = fmaxf(fmaxf(v[0], v[1]), fmaxf(v[2], v[3]));
                        #pragma unroll
                        for (int o = 1; o < 16; o <<= 1) m = fmaxf(m, __shfl_xor(m, o));
                        float e[4], s = 0.f;
                        #pragma unroll
                        for (int ni = 0; ni < 4; ++ni) { e[ni] = __expf(v[ni] - m); s += e[ni]; }
                        #pragma unroll
                        for (int o = 1; o < 16; o <<= 1) s += __shfl_xor(s, o);
                        float rs = 1.f / s;
                        long row = rbase + mi * 16 + rr;
                        #pragma unroll
                        for (int ni = 0; ni < 4; ++ni)
                            Cw[row * 512 + cbase + ni * 16 - 256] = (f16)(e[ni] * rs);
                    }
            } else {
                #pragma unroll
                for (int mi = 0; mi < 4; ++mi)
                    #pragma unroll
                    for (int ni = 0; ni < 4; ++ni)
                        #pragma unroll
                        for (int rr = 0; rr < 4; ++rr)
                            Cfx[(long)(rbase + mi * 16 + rr) * 256 + cbase + ni * 16] =
                                (f16)(acc[mi][ni][rr] + bv[ni]);
            }
        } else {
            #pragma unroll
            for (int mi = 0; mi < 4; ++mi)
                #pragma unroll
                for (int ni = 0; ni < 4; ++ni)
                    #pragma unroll
                    for (int rr = 0; rr < 4; ++rr)
                        Cf[(long)(rbase + mi * 16 + rr) * 256 + cbase + ni * 16] =
                            acc[mi][ni][rr] + bv[ni];
        }
    }
}

// ---------------- K1c: accumulate slice_token partials + slice_norm partials ----------------
__global__ __launch_bounds__(256) void k1c_accum(
    const f16* __restrict__ yfx, const f16* __restrict__ yw,
    float* __restrict__ partials)
{
    int chunk = blockIdx.x & 63;
    int bh = blockIdx.x >> 6;
    int b = bh >> 3, h = bh & 7;
    long tbase = (long)b * NTOK + (long)chunk * 512;

    __shared__ float wl[8][64];
    __shared__ float fxl[8][32];

    int tid = threadIdx.x;
    int d = tid & 31;
    int sg = tid >> 5;  // 0..7

    float acc[8] = {0, 0, 0, 0, 0, 0, 0, 0};
    float nacc = 0.f;

    for (int g = 0; g < 64; ++g) {
        long t0 = tbase + g * 8;
        {
            int idx = tid;
            #pragma unroll
            for (int r = 0; r < 2; ++r, idx += 256) {
                int ti = idx >> 6, s = idx & 63;
                wl[ti][s] = (float)yw[(t0 + ti) * 512 + h * 64 + s];
            }
            int ti = tid >> 5, dd = tid & 31;
            fxl[ti][dd] = (float)yfx[(t0 + ti) * 256 + h * 32 + dd];
        }
        __syncthreads();
        #pragma unroll
        for (int ti = 0; ti < 8; ++ti) {
            float f = fxl[ti][d];
            #pragma unroll
            for (int k = 0; k < 8; ++k)
                acc[k] += wl[ti][sg + 8 * k] * f;
        }
        if (tid < 64) {
            #pragma unroll
            for (int ti = 0; ti < 8; ++ti) nacc += wl[ti][tid];
        }
        __syncthreads();
    }

    float* P = partials + ((long)bh * 64 + chunk) * 2112;
    #pragma unroll
    for (int k = 0; k < 8; ++k) {
        int s = sg + 8 * k;
        P[s * 32 + d] = acc[k];
    }
    if (tid < 64) P[2048 + tid] = nacc;
}

// ---------------- K3: reduce partials, slice attention, build OT2T (f16) ----------------
// OT2T[b][c][h*64+s] = sum_d out_tok[b,h,s,d] * Wout[c][h*32+d]
__global__ __launch_bounds__(256) void k3_slice(
    const float* __restrict__ partials,
    const float* __restrict__ Wqkv,
    const float* __restrict__ Wout,
    f16* __restrict__ OT2T)
{
    __shared__ float smem[14720];
    float* st = smem;          // 64*33
    float* q  = smem + 2112;
    float* kk = smem + 4224;
    float* v  = smem + 6336;
    float* L  = smem + 8448;   // 64*65
    float* red = L;
    float* ot = smem + 12608;  // 64*33

    int bh = blockIdx.x;
    int b = bh >> 3, h = bh & 7;
    int tid = threadIdx.x;

    for (int idx = tid; idx < 2112; idx += 256) {
        float s = 0.f;
        const float* P = partials + (long)bh * 64 * 2112 + idx;
        for (int c = 0; c < 64; ++c) s += P[c * 2112];
        red[idx] = s;
    }
    __syncthreads();
    for (int idx = tid; idx < 2048; idx += 256) {
        int s = idx >> 5, d = idx & 31;
        st[s * 33 + d] = red[idx] / (red[2048 + s] + 0.01f);
    }
    __syncthreads();
    for (int idx = tid; idx < 64 * 96; idx += 256) {
        int s = idx / 96, e = idx % 96;
        float acc = 0.f;
        #pragma unroll
        for (int d = 0; d < 32; ++d) acc += st[s * 33 + d] * Wqkv[e * 32 + d];
        if (e < 32)       q[s * 33 + e] = acc;
        else if (e < 64)  kk[s * 33 + (e - 32)] = acc;
        else              v[s * 33 + (e - 64)] = acc;
    }
    __syncthreads();
    for (int idx = tid; idx < 4096; idx += 256) {
        int i = idx >> 6, j = idx & 63;
        float acc = 0.f;
        #pragma unroll
        for (int d = 0; d < 32; ++d) acc += q[i * 33 + d] * kk[j * 33 + d];
        L[i * 65 + j] = acc * 0.17677669529663687f;
    }
    __syncthreads();
    {
        int lane = tid & 63, wid = tid >> 6;
        for (int r = wid; r < 64; r += 4) {
            float x = L[r * 65 + lane];
            float m = x;
            #pragma unroll
            for (int o = 32; o; o >>= 1) m = fmaxf(m, __shfl_xor(m, o));
            float e = __expf(x - m);
            float ss2 = e;
            #pragma unroll
            for (int o = 32; o; o >>= 1) ss2 += __shfl_xor(ss2, o);
            L[r * 65 + lane] = e / ss2;
        }
    }
    __syncthreads();
    for (int idx = tid; idx < 2048; idx += 256) {
        int s = idx >> 5, d = idx & 31;
        float acc = 0.f;
        #pragma unroll
        for (int j = 0; j < 64; ++j) acc += L[s * 65 + j] * v[j * 33 + d];
        ot[s * 33 + d] = acc;
    }
    __syncthreads();
    float* Wo = smem;  // 256*33
    for (int idx = tid; idx < 8192; idx += 256) {
        int c = idx >> 5, d = idx & 31;
        Wo[c * 33 + d] = Wout[c * 256 + h * 32 + d];
    }
    __syncthreads();
    {
        int c = tid;
        f16* O = OT2T + (long)b * 131072 + (long)c * 512 + h * 64;
        for (int s = 0; s < 64; ++s) {
            float acc = 0.f;
            #pragma unroll
            for (int d = 0; d < 32; ++d) acc += ot[s * 33 + d] * Wo[c * 33 + d];
            O[s] = (f16)acc;
        }
    }
}

extern "C" void kernel_launch(void* const* d_in, const int* in_sizes, int n_in,
                              void* d_out, int out_size, void* d_ws, size_t ws_size,
                              hipStream_t stream) {
    const float* x           = (const float*)d_in[0];
    const float* Wx          = (const float*)d_in[1];
    const float* bx          = (const float*)d_in[2];
    const float* Wfx         = (const float*)d_in[3];
    const float* bfx         = (const float*)d_in[4];
    const float* Wslice      = (const float*)d_in[5];
    const float* bslice      = (const float*)d_in[6];
    const float* Wqkv        = (const float*)d_in[7];
    const float* Wout        = (const float*)d_in[8];
    const float* bout        = (const float*)d_in[9];
    const float* temperature = (const float*)d_in[10];
    float* out = (float*)d_out;

    char* ws = (char*)d_ws;
    f16*   xf16     = (f16*)(ws);                     // 131072*256 f16  =  67108864 B
    f16*   yfx      = (f16*)(ws + 67108864ULL);       // 131072*256 f16  =  67108864 B
    f16*   yw       = (f16*)(ws + 134217728ULL);      // 131072*512 f16  = 134217728 B
    float* partials = (float*)(ws + 268435456ULL);    // 32*64*2112 f32  =  17301504 B
    f16*   Bt       = (f16*)(ws + 285736960ULL);      // 768*256 f16     =    393216 B
    float* bcomb    = (float*)(ws + 286130176ULL);    // 768 f32         =      3072 B
    f16*   OT2T     = (f16*)(ws + 286133248ULL);      // 4*256*512 f16   =   1048576 B (end 287181824)

    // K0: combined weights (f16, [n][k] layout)
    k0_build<<<768, 256, 0, stream>>>(Wx, bx, Wfx, bfx, Wslice, bslice, Bt, bcomb);

    // xcvt: x -> f16 once (removes per-K-step conversion from K1a)
    xcvt<<<2048, 256, 0, stream>>>(x, xf16);

    // K1a: [fx | w] = x @ Bcomb + bcomb, softmax fused on proj cols
    gemm_f16<4, true><<<dim3(NCOL / 128, BNT / 128), 256, 0, stream>>>(
        xf16, Bt, bcomb, nullptr, yfx, yw, temperature, 0L);

    // K1c: pooled partial sums
    k1c_accum<<<32 * 64, 256, 0, stream>>>(yfx, yw, partials);

    // K3: slice attention + OT2T (f16 transposed)
    k3_slice<<<32, 256, 0, stream>>>(partials, Wqkv, Wout, OT2T);

    // K4: out = w @ OT2 + bout  (M=131072, N=256, K=512), pure gload_lds staging
    gemm_f16<8, false><<<dim3(256 / 128, BNT / 128), 256, 0, stream>>>(
        yw, OT2T, bout, out, nullptr, nullptr, nullptr, 131072L);
}

// Round 7
// 382.168 us; speedup vs baseline: 1.6817x; 1.3420x over previous
//
#include <hip/hip_runtime.h>

// Dims
#define NB 4
#define NTOK 32768
#define BNT 131072      // NB*NTOK
#define CDIM 256
#define HH 8
#define NCOL 768        // 256 fx cols + 512 proj cols

typedef _Float16 f16;
typedef __attribute__((ext_vector_type(8))) _Float16 f16x8;
typedef __attribute__((ext_vector_type(4))) _Float16 f16x4;
typedef __attribute__((ext_vector_type(4))) float f32x4;

__device__ inline void gload_lds16(const void* g, void* l) {
    __builtin_amdgcn_global_load_lds(
        (const __attribute__((address_space(1))) void*)g,
        (__attribute__((address_space(3))) void*)l, 16, 0, 0);
}

// ---------------- xcvt: x fp32 -> f16 (row-major, gload-ready) ----------------
__global__ __launch_bounds__(256) void xcvt(
    const float* __restrict__ x, f16* __restrict__ xf)
{
    long i = (long)blockIdx.x * 256 + threadIdx.x;
    const long stride = (long)gridDim.x * 256;
    const long n4 = (long)BNT * CDIM / 4;
    for (; i < n4; i += stride) {
        float4 v = ((const float4*)x)[i];
        f16x4 o = {(f16)v.x, (f16)v.y, (f16)v.z, (f16)v.w};
        *(f16x4*)(xf + i * 4) = o;
    }
}

// ---------------- K0: build combined weight matrix (f16, transposed) ----------------
__global__ __launch_bounds__(256) void k0_build(
    const float* __restrict__ Wx, const float* __restrict__ bx,
    const float* __restrict__ Wfx, const float* __restrict__ bfx,
    const float* __restrict__ Wslice, const float* __restrict__ bslice,
    f16* __restrict__ Bt, float* __restrict__ bcomb)
{
    int col = blockIdx.x;      // 0..767 (output column n)
    int k = threadIdx.x;       // 0..255 (input channel)
    float acc;
    if (col < 256) {
        acc = Wfx[col * 256 + k];
        if (k == 0) bcomb[col] = bfx[col];
    } else {
        int p = col - 256, h = p >> 6, s = p & 63;
        acc = 0.f;
        #pragma unroll
        for (int d = 0; d < 32; ++d)
            acc += Wx[(h * 32 + d) * 256 + k] * Wslice[s * 32 + d];
        if (k == 0) {
            float bacc = bslice[s];
            #pragma unroll
            for (int d = 0; d < 32; ++d)
                bacc += bx[h * 32 + d] * Wslice[s * 32 + d];
            bcomb[col] = bacc;
        }
    }
    Bt[(long)col * 256 + k] = (f16)acc;
}

// ---------------- f16 MFMA GEMM, pure global_load_lds staging ----------------
template<int NSO, bool FUSE_SM>
__global__ __launch_bounds__(256) void gemm_f16(
    const f16* __restrict__ A, const f16* __restrict__ Bt,
    const float* __restrict__ bias, float* __restrict__ Cf,
    f16* __restrict__ Cfx, f16* __restrict__ Cw,
    const float* __restrict__ temperature, long bStrideB)
{
    constexpr int KO = NSO * 64;
    __shared__ f16 sA[128 * 64];
    __shared__ f16 sB[128 * 64];

    const int tid = threadIdx.x;
    const int lane = tid & 63;
    const int w = tid >> 6;
    const int wr = w >> 1, wc = w & 1;

    // XCD-aware bijective swizzle
    const int nx = gridDim.x;
    const int nwg = nx * gridDim.y;
    const int lid = blockIdx.y * nx + blockIdx.x;
    const int swz = (lid & 7) * (nwg >> 3) + (lid >> 3);
    const int m0 = (swz / nx) * 128, n0 = (swz % nx) * 128;

    const f16* BtB = Bt + ((long)m0 >> 15) * bStrideB;  // per-batch B (K4)

    f32x4 acc[4][4] = {};

    for (int cs = 0; cs < NSO; ++cs) {
        __syncthreads();
        #pragma unroll
        for (int i = 0; i < 4; ++i) {
            int li = i * 256 + tid;
            int r = li >> 3, c = li & 7;
            int csrc = c ^ (r & 7);
            int lb = (i * 256 + (tid & ~63)) * 16;   // wave-uniform base
            long off = cs * 64 + csrc * 8;
            gload_lds16(A + (long)(m0 + r) * KO + off, (char*)sA + lb);
            gload_lds16(BtB + (long)(n0 + r) * KO + off, (char*)sB + lb);
        }
        __syncthreads();
        #pragma unroll
        for (int ksub = 0; ksub < 2; ++ksub) {
            int cr = ksub * 4 + (lane >> 4);
            f16x8 a[4], b[4];
            #pragma unroll
            for (int mi = 0; mi < 4; ++mi) {
                int r = wr * 64 + mi * 16 + (lane & 15);
                int off = r * 128 + ((cr ^ (r & 7)) << 4);
                a[mi] = *(const f16x8*)((const char*)sA + off);
            }
            #pragma unroll
            for (int ni = 0; ni < 4; ++ni) {
                int r = wc * 64 + ni * 16 + (lane & 15);
                int off = r * 128 + ((cr ^ (r & 7)) << 4);
                b[ni] = *(const f16x8*)((const char*)sB + off);
            }
            #pragma unroll
            for (int mi = 0; mi < 4; ++mi)
                #pragma unroll
                for (int ni = 0; ni < 4; ++ni)
                    acc[mi][ni] = __builtin_amdgcn_mfma_f32_16x16x32_f16(a[mi], b[ni], acc[mi][ni], 0, 0, 0);
        }
    }
    // --- epilogue: C/D layout col=lane&15, row=(lane>>4)*4+reg ---
    {
        int rbase = m0 + wr * 64 + (lane >> 4) * 4;
        int cbase = n0 + wc * 64 + (lane & 15);
        float bv[4];
        #pragma unroll
        for (int ni = 0; ni < 4; ++ni) bv[ni] = bias[cbase + ni * 16];

        if constexpr (FUSE_SM) {
            bool proj = (n0 + wc * 64) >= 256;   // wave-uniform
            if (proj) {
                int h = (n0 + wc * 64 - 256) >> 6;
                float invt = 1.f / fminf(fmaxf(temperature[h], 0.5f), 5.0f);
                #pragma unroll
                for (int mi = 0; mi < 4; ++mi)
                    #pragma unroll
                    for (int rr = 0; rr < 4; ++rr) {
                        float v[4];
                        #pragma unroll
                        for (int ni = 0; ni < 4; ++ni)
                            v[ni] = (acc[mi][ni][rr] + bv[ni]) * invt;
                        float m = fmaxf(fmaxf(v[0], v[1]), fmaxf(v[2], v[3]));
                        #pragma unroll
                        for (int o = 1; o < 16; o <<= 1) m = fmaxf(m, __shfl_xor(m, o));
                        float e[4], s = 0.f;
                        #pragma unroll
                        for (int ni = 0; ni < 4; ++ni) { e[ni] = __expf(v[ni] - m); s += e[ni]; }
                        #pragma unroll
                        for (int o = 1; o < 16; o <<= 1) s += __shfl_xor(s, o);
                        float rs = 1.f / s;
                        long row = rbase + mi * 16 + rr;
                        #pragma unroll
                        for (int ni = 0; ni < 4; ++ni)
                            Cw[row * 512 + cbase + ni * 16 - 256] = (f16)(e[ni] * rs);
                    }
            } else {
                #pragma unroll
                for (int mi = 0; mi < 4; ++mi)
                    #pragma unroll
                    for (int ni = 0; ni < 4; ++ni)
                        #pragma unroll
                        for (int rr = 0; rr < 4; ++rr)
                            Cfx[(long)(rbase + mi * 16 + rr) * 256 + cbase + ni * 16] =
                                (f16)(acc[mi][ni][rr] + bv[ni]);
            }
        } else {
            #pragma unroll
            for (int mi = 0; mi < 4; ++mi)
                #pragma unroll
                for (int ni = 0; ni < 4; ++ni)
                    #pragma unroll
                    for (int rr = 0; rr < 4; ++rr)
                        Cf[(long)(rbase + mi * 16 + rr) * 256 + cbase + ni * 16] =
                            acc[mi][ni][rr] + bv[ni];
        }
    }
}

// ---------------- K1c (MFMA): slice_token + slice_norm partials via matrix pipe ----
// Per (b,h): ST[s][d] = sum_n w[n][s]*fx[n][d]; norm[s] = sum_n w[n][s].
// A-operand = w^T (transposed LDS reads), B = fx; norm via constant ones-B-frag.
// LDS: w [4 chunks][32 t][64 s] f16, phys chunk = sc ^ ((t>>3)<<1)  (16 KB)
//      fx [4][32][32 d] f16 at 16384, phys chunk = dc ^ (t>>3)     (8 KB)
//      red [4 waves][64 s][36] f32 overlaps after compute          (36864 B)
__global__ __launch_bounds__(256) void k1c_mfma(
    const f16* __restrict__ yfx, const f16* __restrict__ yw,
    float* __restrict__ partials)
{
    __shared__ char lds[36864];

    const int tid = threadIdx.x;
    const int lane = tid & 63;
    const int wv = tid >> 6;
    const int chunk64 = blockIdx.x & 63;
    const int bh = blockIdx.x >> 6;
    const int b = bh >> 3, h = bh & 7;
    const long tbase = (long)b * NTOK + (long)chunk64 * 512;

    f32x4 acc[4][3] = {};

    // constant ones B-fragment: lane holds col d = lane&15; B[k][0] = 1
    const f16 oe = ((lane & 15) == 0) ? (f16)1.0f : (f16)0.0f;
    const f16x8 bones = {oe, oe, oe, oe, oe, oe, oe, oe};

    const int g = lane >> 4;

    for (int iter = 0; iter < 4; ++iter) {
        const long t0 = tbase + iter * 128;
        __syncthreads();   // previous compute's LDS reads done
        // --- stage w: 16 slots x 1KB; wave wv issues its own chunk's slots ---
        #pragma unroll
        for (int i = 0; i < 4; ++i) {
            int k = wv * 4 + i;
            int sc = (lane & 7) ^ ((k & 3) << 1);
            const f16* src = yw + (t0 + k * 8 + (lane >> 3)) * 512 + h * 64 + sc * 8;
            gload_lds16(src, lds + k * 1024);
        }
        // --- stage fx: 8 slots x 1KB ---
        #pragma unroll
        for (int i = 0; i < 2; ++i) {
            int k = wv * 2 + i;
            int tq = (k & 1) * 16 + (lane >> 2);
            int dc = (lane & 3) ^ ((tq >> 3) & 3);
            const f16* src = yfx + (t0 + k * 16 + (lane >> 2)) * 256 + h * 32 + dc * 8;
            gload_lds16(src, lds + 16384 + k * 1024);
        }
        __syncthreads();   // drains vmcnt
        // --- compute: wave wv consumes chunk wv (32 tokens) ---
        f16x8 a[4], bf[2];
        #pragma unroll
        for (int st = 0; st < 4; ++st) {
            int srow = st * 16 + (lane & 15);
            int schunk = (srow >> 3) ^ (g << 1);
            int base = wv * 4096 + g * 1024 + (schunk << 4) + (srow & 7) * 2;
            #pragma unroll
            for (int j = 0; j < 8; ++j)
                a[st][j] = *(const f16*)(lds + base + j * 128);
        }
        #pragma unroll
        for (int dt = 0; dt < 2; ++dt) {
            int d = dt * 16 + (lane & 15);
            int dchunk = ((d >> 3) ^ g) & 3;
            int base = 16384 + wv * 2048 + g * 512 + (dchunk << 4) + (d & 7) * 2;
            #pragma unroll
            for (int j = 0; j < 8; ++j)
                bf[dt][j] = *(const f16*)(lds + base + j * 64);
        }
        #pragma unroll
        for (int st = 0; st < 4; ++st) {
            acc[st][0] = __builtin_amdgcn_mfma_f32_16x16x32_f16(a[st], bf[0], acc[st][0], 0, 0, 0);
            acc[st][1] = __builtin_amdgcn_mfma_f32_16x16x32_f16(a[st], bf[1], acc[st][1], 0, 0, 0);
            acc[st][2] = __builtin_amdgcn_mfma_f32_16x16x32_f16(a[st], bones, acc[st][2], 0, 0, 0);
        }
    }
    // --- cross-wave reduce: red[4][64][36] f32 overlapping the tiles ---
    __syncthreads();
    float* red = (float*)lds;
    #pragma unroll
    for (int st = 0; st < 4; ++st) {
        #pragma unroll
        for (int rr = 0; rr < 4; ++rr) {
            int s = st * 16 + g * 4 + rr;
            red[(wv * 64 + s) * 36 + (lane & 15)] = acc[st][0][rr];
            red[(wv * 64 + s) * 36 + 16 + (lane & 15)] = acc[st][1][rr];
            if ((lane & 15) == 0)
                red[(wv * 64 + s) * 36 + 32] = acc[st][2][rr];
        }
    }
    __syncthreads();
    float* P = partials + ((long)bh * 64 + chunk64) * 2112;
    for (int idx = tid; idx < 2112; idx += 256) {
        int s, c;
        if (idx < 2048) { s = idx >> 5; c = idx & 31; }
        else            { s = idx - 2048; c = 32; }
        float v = red[s * 36 + c] + red[(64 + s) * 36 + c]
                + red[(128 + s) * 36 + c] + red[(192 + s) * 36 + c];
        P[idx] = v;
    }
}

// ---------------- K3: reduce partials, slice attention, build OT2T (f16) ----------------
__global__ __launch_bounds__(256) void k3_slice(
    const float* __restrict__ partials,
    const float* __restrict__ Wqkv,
    const float* __restrict__ Wout,
    f16* __restrict__ OT2T)
{
    __shared__ float smem[14720];
    float* st = smem;          // 64*33
    float* q  = smem + 2112;
    float* kk = smem + 4224;
    float* v  = smem + 6336;
    float* L  = smem + 8448;   // 64*65
    float* red = L;
    float* ot = smem + 12608;  // 64*33

    int bh = blockIdx.x;
    int b = bh >> 3, h = bh & 7;
    int tid = threadIdx.x;

    for (int idx = tid; idx < 2112; idx += 256) {
        float s = 0.f;
        const float* P = partials + (long)bh * 64 * 2112 + idx;
        for (int c = 0; c < 64; ++c) s += P[c * 2112];
        red[idx] = s;
    }
    __syncthreads();
    for (int idx = tid; idx < 2048; idx += 256) {
        int s = idx >> 5, d = idx & 31;
        st[s * 33 + d] = red[idx] / (red[2048 + s] + 0.01f);
    }
    __syncthreads();
    for (int idx = tid; idx < 64 * 96; idx += 256) {
        int s = idx / 96, e = idx % 96;
        float acc = 0.f;
        #pragma unroll
        for (int d = 0; d < 32; ++d) acc += st[s * 33 + d] * Wqkv[e * 32 + d];
        if (e < 32)       q[s * 33 + e] = acc;
        else if (e < 64)  kk[s * 33 + (e - 32)] = acc;
        else              v[s * 33 + (e - 64)] = acc;
    }
    __syncthreads();
    for (int idx = tid; idx < 4096; idx += 256) {
        int i = idx >> 6, j = idx & 63;
        float acc = 0.f;
        #pragma unroll
        for (int d = 0; d < 32; ++d) acc += q[i * 33 + d] * kk[j * 33 + d];
        L[i * 65 + j] = acc * 0.17677669529663687f;
    }
    __syncthreads();
    {
        int lane = tid & 63, wid = tid >> 6;
        for (int r = wid; r < 64; r += 4) {
            float x = L[r * 65 + lane];
            float m = x;
            #pragma unroll
            for (int o = 32; o; o >>= 1) m = fmaxf(m, __shfl_xor(m, o));
            float e = __expf(x - m);
            float ss2 = e;
            #pragma unroll
            for (int o = 32; o; o >>= 1) ss2 += __shfl_xor(ss2, o);
            L[r * 65 + lane] = e / ss2;
        }
    }
    __syncthreads();
    for (int idx = tid; idx < 2048; idx += 256) {
        int s = idx >> 5, d = idx & 31;
        float acc = 0.f;
        #pragma unroll
        for (int j = 0; j < 64; ++j) acc += L[s * 65 + j] * v[j * 33 + d];
        ot[s * 33 + d] = acc;
    }
    __syncthreads();
    float* Wo = smem;  // 256*33
    for (int idx = tid; idx < 8192; idx += 256) {
        int c = idx >> 5, d = idx & 31;
        Wo[c * 33 + d] = Wout[c * 256 + h * 32 + d];
    }
    __syncthreads();
    {
        int c = tid;
        f16* O = OT2T + (long)b * 131072 + (long)c * 512 + h * 64;
        for (int s = 0; s < 64; ++s) {
            float acc = 0.f;
            #pragma unroll
            for (int d = 0; d < 32; ++d) acc += ot[s * 33 + d] * Wo[c * 33 + d];
            O[s] = (f16)acc;
        }
    }
}

extern "C" void kernel_launch(void* const* d_in, const int* in_sizes, int n_in,
                              void* d_out, int out_size, void* d_ws, size_t ws_size,
                              hipStream_t stream) {
    const float* x           = (const float*)d_in[0];
    const float* Wx          = (const float*)d_in[1];
    const float* bx          = (const float*)d_in[2];
    const float* Wfx         = (const float*)d_in[3];
    const float* bfx         = (const float*)d_in[4];
    const float* Wslice      = (const float*)d_in[5];
    const float* bslice      = (const float*)d_in[6];
    const float* Wqkv        = (const float*)d_in[7];
    const float* Wout        = (const float*)d_in[8];
    const float* bout        = (const float*)d_in[9];
    const float* temperature = (const float*)d_in[10];
    float* out = (float*)d_out;

    char* ws = (char*)d_ws;
    f16*   xf16     = (f16*)(ws);                     // 131072*256 f16  =  67108864 B
    f16*   yfx      = (f16*)(ws + 67108864ULL);       // 131072*256 f16  =  67108864 B
    f16*   yw       = (f16*)(ws + 134217728ULL);      // 131072*512 f16  = 134217728 B
    float* partials = (float*)(ws + 268435456ULL);    // 32*64*2112 f32  =  17301504 B
    f16*   Bt       = (f16*)(ws + 285736960ULL);      // 768*256 f16     =    393216 B
    float* bcomb    = (float*)(ws + 286130176ULL);    // 768 f32         =      3072 B
    f16*   OT2T     = (f16*)(ws + 286133248ULL);      // 4*256*512 f16   =   1048576 B (end 287181824)

    // K0: combined weights (f16, [n][k] layout)
    k0_build<<<768, 256, 0, stream>>>(Wx, bx, Wfx, bfx, Wslice, bslice, Bt, bcomb);

    // xcvt: x -> f16 once
    xcvt<<<2048, 256, 0, stream>>>(x, xf16);

    // K1a: [fx | w] = x @ Bcomb + bcomb, softmax fused on proj cols
    gemm_f16<4, true><<<dim3(NCOL / 128, BNT / 128), 256, 0, stream>>>(
        xf16, Bt, bcomb, nullptr, yfx, yw, temperature, 0L);

    // K1c: pooled partial sums via MFMA
    k1c_mfma<<<32 * 64, 256, 0, stream>>>(yfx, yw, partials);

    // K3: slice attention + OT2T (f16 transposed)
    k3_slice<<<32, 256, 0, stream>>>(partials, Wqkv, Wout, OT2T);

    // K4: out = w @ OT2 + bout  (M=131072, N=256, K=512), pure gload_lds staging
    gemm_f16<8, false><<<dim3(256 / 128, BNT / 128), 256, 0, stream>>>(
        yw, OT2T, bout, out, nullptr, nullptr, nullptr, 131072L);
}

// Round 8
// 375.391 us; speedup vs baseline: 1.7120x; 1.0181x over previous
//
#include <hip/hip_runtime.h>

// Dims
#define NB 4
#define NTOK 32768
#define BNT 131072      // NB*NTOK
#define CDIM 256
#define HH 8
#define NCOL 768        // 256 fx cols + 512 proj cols

typedef _Float16 f16;
typedef __attribute__((ext_vector_type(8))) _Float16 f16x8;
typedef __attribute__((ext_vector_type(4))) _Float16 f16x4;
typedef __attribute__((ext_vector_type(4))) float f32x4;

__device__ inline void gload_lds16(const void* g, void* l) {
    __builtin_amdgcn_global_load_lds(
        (const __attribute__((address_space(1))) void*)g,
        (__attribute__((address_space(3))) void*)l, 16, 0, 0);
}

// ---------------- xcvt: x fp32 -> f16 (row-major, gload-ready) ----------------
__global__ __launch_bounds__(256) void xcvt(
    const float* __restrict__ x, f16* __restrict__ xf)
{
    long i = (long)blockIdx.x * 256 + threadIdx.x;
    const long stride = (long)gridDim.x * 256;
    const long n4 = (long)BNT * CDIM / 4;
    for (; i < n4; i += stride) {
        float4 v = ((const float4*)x)[i];
        f16x4 o = {(f16)v.x, (f16)v.y, (f16)v.z, (f16)v.w};
        *(f16x4*)(xf + i * 4) = o;
    }
}

// ---------------- K0: build combined weight matrix (f16, transposed) ----------------
__global__ __launch_bounds__(256) void k0_build(
    const float* __restrict__ Wx, const float* __restrict__ bx,
    const float* __restrict__ Wfx, const float* __restrict__ bfx,
    const float* __restrict__ Wslice, const float* __restrict__ bslice,
    f16* __restrict__ Bt, float* __restrict__ bcomb)
{
    int col = blockIdx.x;      // 0..767 (output column n)
    int k = threadIdx.x;       // 0..255 (input channel)
    float acc;
    if (col < 256) {
        acc = Wfx[col * 256 + k];
        if (k == 0) bcomb[col] = bfx[col];
    } else {
        int p = col - 256, h = p >> 6, s = p & 63;
        acc = 0.f;
        #pragma unroll
        for (int d = 0; d < 32; ++d)
            acc += Wx[(h * 32 + d) * 256 + k] * Wslice[s * 32 + d];
        if (k == 0) {
            float bacc = bslice[s];
            #pragma unroll
            for (int d = 0; d < 32; ++d)
                bacc += bx[h * 32 + d] * Wslice[s * 32 + d];
            bcomb[col] = bacc;
        }
    }
    Bt[(long)col * 256 + k] = (f16)acc;
}

// ---------------- f16 MFMA GEMM, 2-phase dbuf global_load_lds staging ----------------
// 128x128 tile, 4 waves (2x2), 16x16x32 f16 MFMA, XOR-swizzled LDS (via
// pre-swizzled global source), XCD-bijective block swizzle (nwg%8==0).
// Loop: STAGE(t+1, buf^1) -> compute(t, buf) -> __syncthreads (drain overlapped).
template<int NSO, bool FUSE_SM>
__global__ __launch_bounds__(256) void gemm_f16(
    const f16* __restrict__ A, const f16* __restrict__ Bt,
    const float* __restrict__ bias, float* __restrict__ Cf,
    f16* __restrict__ Cfx, f16* __restrict__ Cw,
    const float* __restrict__ temperature, long bStrideB)
{
    constexpr int KO = NSO * 64;
    __shared__ char lds[65536];   // [2] x { sA 16KB | sB 16KB }

    const int tid = threadIdx.x;
    const int lane = tid & 63;
    const int w = tid >> 6;
    const int wr = w >> 1, wc = w & 1;

    // XCD-aware bijective swizzle
    const int nx = gridDim.x;
    const int nwg = nx * gridDim.y;
    const int lid = blockIdx.y * nx + blockIdx.x;
    const int swz = (lid & 7) * (nwg >> 3) + (lid >> 3);
    const int m0 = (swz / nx) * 128, n0 = (swz % nx) * 128;

    const f16* BtB = Bt + ((long)m0 >> 15) * bStrideB;  // per-batch B (K4)

    f32x4 acc[4][4] = {};

    auto stage = [&](int cs, int buf) {
        char* sa = lds + buf * 32768;
        char* sb = sa + 16384;
        #pragma unroll
        for (int i = 0; i < 4; ++i) {
            int li = i * 256 + tid;
            int r = li >> 3, c = li & 7;
            int csrc = c ^ (r & 7);
            int lb = (i * 256 + (tid & ~63)) * 16;   // wave-uniform base
            long off = (long)cs * 64 + csrc * 8;
            gload_lds16(A + (long)(m0 + r) * KO + off, sa + lb);
            gload_lds16(BtB + (long)(n0 + r) * KO + off, sb + lb);
        }
    };

    stage(0, 0);
    __syncthreads();
    for (int cs = 0; cs < NSO; ++cs) {
        const int buf = cs & 1;
        if (cs + 1 < NSO) stage(cs + 1, buf ^ 1);   // prefetch overlaps compute
        const char* sa = lds + buf * 32768;
        const char* sb = sa + 16384;
        #pragma unroll
        for (int ksub = 0; ksub < 2; ++ksub) {
            int cr = ksub * 4 + (lane >> 4);
            f16x8 a[4], b[4];
            #pragma unroll
            for (int mi = 0; mi < 4; ++mi) {
                int r = wr * 64 + mi * 16 + (lane & 15);
                a[mi] = *(const f16x8*)(sa + r * 128 + ((cr ^ (r & 7)) << 4));
            }
            #pragma unroll
            for (int ni = 0; ni < 4; ++ni) {
                int r = wc * 64 + ni * 16 + (lane & 15);
                b[ni] = *(const f16x8*)(sb + r * 128 + ((cr ^ (r & 7)) << 4));
            }
            #pragma unroll
            for (int mi = 0; mi < 4; ++mi)
                #pragma unroll
                for (int ni = 0; ni < 4; ++ni)
                    acc[mi][ni] = __builtin_amdgcn_mfma_f32_16x16x32_f16(a[mi], b[ni], acc[mi][ni], 0, 0, 0);
        }
        __syncthreads();   // drains vmcnt (prefetch landed during compute)
    }
    // --- epilogue: C/D layout col=lane&15, row=(lane>>4)*4+reg ---
    {
        int rloc0 = wr * 64 + (lane >> 4) * 4;   // + mi*16 + rr
        int cloc0 = wc * 64 + (lane & 15);       // + ni*16
        float bv[4];
        #pragma unroll
        for (int ni = 0; ni < 4; ++ni) bv[ni] = bias[n0 + cloc0 + ni * 16];

        if constexpr (FUSE_SM) {
            // whole block tile routes to ONE output (n-tiles are 128-wide, 256-aligned split)
            f16* stile = (f16*)lds;    // [128][132] padded
            bool proj = n0 >= 256;     // block-uniform
            if (proj) {
                int h = (n0 - 256 + wc * 64) >> 6;
                float invt = 1.f / fminf(fmaxf(temperature[h], 0.5f), 5.0f);
                #pragma unroll
                for (int mi = 0; mi < 4; ++mi)
                    #pragma unroll
                    for (int rr = 0; rr < 4; ++rr) {
                        float v[4];
                        #pragma unroll
                        for (int ni = 0; ni < 4; ++ni)
                            v[ni] = (acc[mi][ni][rr] + bv[ni]) * invt;
                        float m = fmaxf(fmaxf(v[0], v[1]), fmaxf(v[2], v[3]));
                        #pragma unroll
                        for (int o = 1; o < 16; o <<= 1) m = fmaxf(m, __shfl_xor(m, o));
                        float e[4], s = 0.f;
                        #pragma unroll
                        for (int ni = 0; ni < 4; ++ni) { e[ni] = __expf(v[ni] - m); s += e[ni]; }
                        #pragma unroll
                        for (int o = 1; o < 16; o <<= 1) s += __shfl_xor(s, o);
                        float rs = 1.f / s;
                        int rloc = rloc0 + mi * 16 + rr;
                        #pragma unroll
                        for (int ni = 0; ni < 4; ++ni)
                            stile[rloc * 132 + cloc0 + ni * 16] = (f16)(e[ni] * rs);
                    }
            } else {
                #pragma unroll
                for (int mi = 0; mi < 4; ++mi)
                    #pragma unroll
                    for (int rr = 0; rr < 4; ++rr) {
                        int rloc = rloc0 + mi * 16 + rr;
                        #pragma unroll
                        for (int ni = 0; ni < 4; ++ni)
                            stile[rloc * 132 + cloc0 + ni * 16] =
                                (f16)(acc[mi][ni][rr] + bv[ni]);
                    }
            }
            __syncthreads();
            f16* dst = proj ? (Cw + (long)m0 * 512 + (n0 - 256))
                            : (Cfx + (long)m0 * 256 + n0);
            const int ld = proj ? 512 : 256;
            #pragma unroll
            for (int i = 0; i < 8; ++i) {
                int idx = i * 256 + tid;
                int r = idx >> 4, c = idx & 15;
                *(f16x8*)(dst + (long)r * ld + c * 8) =
                    *(const f16x8*)(stile + r * 132 + c * 8);
            }
        } else {
            #pragma unroll
            for (int mi = 0; mi < 4; ++mi)
                #pragma unroll
                for (int ni = 0; ni < 4; ++ni)
                    #pragma unroll
                    for (int rr = 0; rr < 4; ++rr)
                        Cf[(long)(m0 + rloc0 + mi * 16 + rr) * 256 + n0 + cloc0 + ni * 16] =
                            acc[mi][ni][rr] + bv[ni];
        }
    }
}

// ---------------- K1c (MFMA): slice_token + slice_norm partials via matrix pipe ----
// Each wave stages and consumes ONLY its own LDS slots -> barrier-free loop with
// counted vmcnt (T4). Double-buffered (2 x 24KB); red[4][64][36] overlays after.
__global__ __launch_bounds__(256) void k1c_mfma(
    const f16* __restrict__ yfx, const f16* __restrict__ yw,
    float* __restrict__ partials)
{
    __shared__ char lds[49152];

    const int tid = threadIdx.x;
    const int lane = tid & 63;
    const int wv = tid >> 6;
    const int chunk64 = blockIdx.x & 63;
    const int bh = blockIdx.x >> 6;
    const int b = bh >> 3, h = bh & 7;
    const long tbase = (long)b * NTOK + (long)chunk64 * 512;

    f32x4 acc[4][3] = {};

    const f16 oe = ((lane & 15) == 0) ? (f16)1.0f : (f16)0.0f;
    const f16x8 bones = {oe, oe, oe, oe, oe, oe, oe, oe};
    const int g = lane >> 4;

    auto stage = [&](int iter, int buf) {
        const long t0 = tbase + iter * 128;
        char* base = lds + buf * 24576;
        #pragma unroll
        for (int i = 0; i < 4; ++i) {
            int k = wv * 4 + i;
            int sc = (lane & 7) ^ ((k & 3) << 1);
            gload_lds16(yw + (t0 + k * 8 + (lane >> 3)) * 512 + h * 64 + sc * 8,
                        base + k * 1024);
        }
        #pragma unroll
        for (int i = 0; i < 2; ++i) {
            int k = wv * 2 + i;
            int tq = (k & 1) * 16 + (lane >> 2);
            int dc = (lane & 3) ^ ((tq >> 3) & 3);
            gload_lds16(yfx + (t0 + k * 16 + (lane >> 2)) * 256 + h * 32 + dc * 8,
                        base + 16384 + k * 1024);
        }
    };

    stage(0, 0);
    for (int iter = 0; iter < 4; ++iter) {
        const int buf = iter & 1;
        if (iter < 3) {
            stage(iter + 1, buf ^ 1);
            asm volatile("s_waitcnt vmcnt(6)" ::: "memory");  // 6 newest in flight
        } else {
            asm volatile("s_waitcnt vmcnt(0)" ::: "memory");
        }
        __builtin_amdgcn_sched_barrier(0);
        const char* base = lds + buf * 24576;
        f16x8 a[4], bf[2];
        #pragma unroll
        for (int st = 0; st < 4; ++st) {
            int srow = st * 16 + (lane & 15);
            int schunk = (srow >> 3) ^ (g << 1);
            int off = wv * 4096 + g * 1024 + (schunk << 4) + (srow & 7) * 2;
            #pragma unroll
            for (int j = 0; j < 8; ++j)
                a[st][j] = *(const f16*)(base + off + j * 128);
        }
        #pragma unroll
        for (int dt = 0; dt < 2; ++dt) {
            int d = dt * 16 + (lane & 15);
            int dchunk = ((d >> 3) ^ g) & 3;
            int off = 16384 + wv * 2048 + g * 512 + (dchunk << 4) + (d & 7) * 2;
            #pragma unroll
            for (int j = 0; j < 8; ++j)
                bf[dt][j] = *(const f16*)(base + off + j * 64);
        }
        #pragma unroll
        for (int st = 0; st < 4; ++st) {
            acc[st][0] = __builtin_amdgcn_mfma_f32_16x16x32_f16(a[st], bf[0], acc[st][0], 0, 0, 0);
            acc[st][1] = __builtin_amdgcn_mfma_f32_16x16x32_f16(a[st], bf[1], acc[st][1], 0, 0, 0);
            acc[st][2] = __builtin_amdgcn_mfma_f32_16x16x32_f16(a[st], bones, acc[st][2], 0, 0, 0);
        }
    }
    // --- cross-wave reduce ---
    __syncthreads();
    float* red = (float*)lds;
    #pragma unroll
    for (int st = 0; st < 4; ++st) {
        #pragma unroll
        for (int rr = 0; rr < 4; ++rr) {
            int s = st * 16 + g * 4 + rr;
            red[(wv * 64 + s) * 36 + (lane & 15)] = acc[st][0][rr];
            red[(wv * 64 + s) * 36 + 16 + (lane & 15)] = acc[st][1][rr];
            if ((lane & 15) == 0)
                red[(wv * 64 + s) * 36 + 32] = acc[st][2][rr];
        }
    }
    __syncthreads();
    float* P = partials + ((long)bh * 64 + chunk64) * 2112;
    for (int idx = tid; idx < 2112; idx += 256) {
        int s, c;
        if (idx < 2048) { s = idx >> 5; c = idx & 31; }
        else            { s = idx - 2048; c = 32; }
        float v = red[s * 36 + c] + red[(64 + s) * 36 + c]
                + red[(128 + s) * 36 + c] + red[(192 + s) * 36 + c];
        P[idx] = v;
    }
}

// ---------------- K3: reduce partials, slice attention, build OT2T (f16) ----------------
__global__ __launch_bounds__(256) void k3_slice(
    const float* __restrict__ partials,
    const float* __restrict__ Wqkv,
    const float* __restrict__ Wout,
    f16* __restrict__ OT2T)
{
    __shared__ float smem[14720];
    float* st = smem;          // 64*33
    float* q  = smem + 2112;
    float* kk = smem + 4224;
    float* v  = smem + 6336;
    float* L  = smem + 8448;   // 64*65
    float* red = L;
    float* ot = smem + 12608;  // 64*33

    int bh = blockIdx.x;
    int b = bh >> 3, h = bh & 7;
    int tid = threadIdx.x;

    for (int idx = tid; idx < 2112; idx += 256) {
        float s = 0.f;
        const float* P = partials + (long)bh * 64 * 2112 + idx;
        for (int c = 0; c < 64; ++c) s += P[c * 2112];
        red[idx] = s;
    }
    __syncthreads();
    for (int idx = tid; idx < 2048; idx += 256) {
        int s = idx >> 5, d = idx & 31;
        st[s * 33 + d] = red[idx] / (red[2048 + s] + 0.01f);
    }
    __syncthreads();
    for (int idx = tid; idx < 64 * 96; idx += 256) {
        int s = idx / 96, e = idx % 96;
        float acc = 0.f;
        #pragma unroll
        for (int d = 0; d < 32; ++d) acc += st[s * 33 + d] * Wqkv[e * 32 + d];
        if (e < 32)       q[s * 33 + e] = acc;
        else if (e < 64)  kk[s * 33 + (e - 32)] = acc;
        else              v[s * 33 + (e - 64)] = acc;
    }
    __syncthreads();
    for (int idx = tid; idx < 4096; idx += 256) {
        int i = idx >> 6, j = idx & 63;
        float acc = 0.f;
        #pragma unroll
        for (int d = 0; d < 32; ++d) acc += q[i * 33 + d] * kk[j * 33 + d];
        L[i * 65 + j] = acc * 0.17677669529663687f;
    }
    __syncthreads();
    {
        int lane = tid & 63, wid = tid >> 6;
        for (int r = wid; r < 64; r += 4) {
            float x = L[r * 65 + lane];
            float m = x;
            #pragma unroll
            for (int o = 32; o; o >>= 1) m = fmaxf(m, __shfl_xor(m, o));
            float e = __expf(x - m);
            float ss2 = e;
            #pragma unroll
            for (int o = 32; o; o >>= 1) ss2 += __shfl_xor(ss2, o);
            L[r * 65 + lane] = e / ss2;
        }
    }
    __syncthreads();
    for (int idx = tid; idx < 2048; idx += 256) {
        int s = idx >> 5, d = idx & 31;
        float acc = 0.f;
        #pragma unroll
        for (int j = 0; j < 64; ++j) acc += L[s * 65 + j] * v[j * 33 + d];
        ot[s * 33 + d] = acc;
    }
    __syncthreads();
    float* Wo = smem;  // 256*33
    for (int idx = tid; idx < 8192; idx += 256) {
        int c = idx >> 5, d = idx & 31;
        Wo[c * 33 + d] = Wout[c * 256 + h * 32 + d];
    }
    __syncthreads();
    {
        int c = tid;
        f16* O = OT2T + (long)b * 131072 + (long)c * 512 + h * 64;
        for (int s = 0; s < 64; ++s) {
            float acc = 0.f;
            #pragma unroll
            for (int d = 0; d < 32; ++d) acc += ot[s * 33 + d] * Wo[c * 33 + d];
            O[s] = (f16)acc;
        }
    }
}

extern "C" void kernel_launch(void* const* d_in, const int* in_sizes, int n_in,
                              void* d_out, int out_size, void* d_ws, size_t ws_size,
                              hipStream_t stream) {
    const float* x           = (const float*)d_in[0];
    const float* Wx          = (const float*)d_in[1];
    const float* bx          = (const float*)d_in[2];
    const float* Wfx         = (const float*)d_in[3];
    const float* bfx         = (const float*)d_in[4];
    const float* Wslice      = (const float*)d_in[5];
    const float* bslice      = (const float*)d_in[6];
    const float* Wqkv        = (const float*)d_in[7];
    const float* Wout        = (const float*)d_in[8];
    const float* bout        = (const float*)d_in[9];
    const float* temperature = (const float*)d_in[10];
    float* out = (float*)d_out;

    char* ws = (char*)d_ws;
    f16*   xf16     = (f16*)(ws);                     // 131072*256 f16  =  67108864 B
    f16*   yfx      = (f16*)(ws + 67108864ULL);      // 131072*256 f16  =  67108864 B
    f16*   yw       = (f16*)(ws + 134217728ULL);     // 131072*512 f16  = 134217728 B
    float* partials = (float*)(ws + 268435456ULL);   // 32*64*2112 f32  =  17301504 B
    f16*   Bt       = (f16*)(ws + 285736960ULL);     // 768*256 f16     =    393216 B
    float* bcomb    = (float*)(ws + 286130176ULL);   // 768 f32         =      3072 B
    f16*   OT2T     = (f16*)(ws + 286133248ULL);     // 4*256*512 f16   =   1048576 B (end 287181824)

    // K0: combined weights (f16, [n][k] layout)
    k0_build<<<768, 256, 0, stream>>>(Wx, bx, Wfx, bfx, Wslice, bslice, Bt, bcomb);

    // xcvt: x -> f16 once
    xcvt<<<2048, 256, 0, stream>>>(x, xf16);

    // K1a: [fx | w] = x @ Bcomb + bcomb, softmax fused on proj cols
    gemm_f16<4, true><<<dim3(NCOL / 128, BNT / 128), 256, 0, stream>>>(
        xf16, Bt, bcomb, nullptr, yfx, yw, temperature, 0L);

    // K1c: pooled partial sums via MFMA (barrier-free, counted vmcnt)
    k1c_mfma<<<32 * 64, 256, 0, stream>>>(yfx, yw, partials);

    // K3: slice attention + OT2T (f16 transposed)
    k3_slice<<<32, 256, 0, stream>>>(partials, Wqkv, Wout, OT2T);

    // K4: out = w @ OT2 + bout  (M=131072, N=256, K=512), dbuf gload staging
    gemm_f16<8, false><<<dim3(256 / 128, BNT / 128), 256, 0, stream>>>(
        yw, OT2T, bout, out, nullptr, nullptr, nullptr, 131072L);
}